// Round 1
// 205.620 us; speedup vs baseline: 1.0342x; 1.0342x over previous
//
#include <hip/hip_runtime.h>
#include <math.h>

#define B_ 32
#define C_ 3
#define H_ 512
#define W_ 512
#define NOUT 64
#define FAN (C_*H_*W_)          // 786432

// locnet decomposition
#define CHUNKS 192
#define CELEMS (FAN / CHUNKS)   // 4096
#define BGROUPS 4               // 8 batches per block
#define NREP 8                  // replicated p-accumulator slots

// workspace layout:
//   floats [0, 2048): NREP x 256 replicated p accumulators (zeroed each call)
//   then ushort images (base = ws + 2048 floats):
//     FxH [32][64][512], FxL, FyH, FyL  (1,048,576 ushorts = 2MB each)
#define PFLOATS 2048
#define FXH_U 0
#define FXL_U 1048576
#define FYH_U 2097152
#define FYL_U 3145728

typedef __bf16 bf16x8 __attribute__((ext_vector_type(8)));
typedef float f32x4 __attribute__((ext_vector_type(4)));

// round-to-nearest-even fp32 -> bf16 (as ushort) — integer emulation (exact RNE)
__device__ __forceinline__ unsigned short f2bf(float f) {
    unsigned int u = __float_as_uint(f);
    u = (u + 0x7FFFu + ((u >> 16) & 1u)) >> 16;
    return (unsigned short)u;
}
__device__ __forceinline__ float bf2f(unsigned short h) {
    return __uint_as_float(((unsigned int)h) << 16);
}
// packed fp32x2 -> bf16x2 in one VALU op (hw RNE; identical results to f2bf)
__device__ __forceinline__ unsigned int cvt_pk_bf16(float lo, float hi) {
    unsigned int r;
    asm("v_cvt_pk_bf16_f32 %0, %1, %2" : "=v"(r) : "v"(lo), "v"(hi));
    return r;
}

// ---------------- kernel 1: p[b,j] = sum_i X[b,i] * W_loc[i,j] ----------------
__global__ __launch_bounds__(256) void k_locnet(const float* __restrict__ X,
                                                const float* __restrict__ Wl,
                                                float* __restrict__ ws) {
    const int chunk = blockIdx.x;      // 0..CHUNKS-1
    const int b0 = blockIdx.y * 8;     // 0,8,16,24
    const int t = threadIdx.x;
    const int rep = chunk & (NREP - 1);

    float acc[8][5] = {};
    const size_t base = (size_t)chunk * CELEMS;

    for (int k = t; k < CELEMS / 4; k += 256) {   // 4 iterations
        const size_t i0 = base + (size_t)k * 4;
        const float4* W4 = (const float4*)(Wl + i0 * 5);
        float4 w0 = W4[0], w1 = W4[1], w2 = W4[2], w3 = W4[3], w4 = W4[4];
        float wv[20] = {w0.x, w0.y, w0.z, w0.w,
                        w1.x, w1.y, w1.z, w1.w,
                        w2.x, w2.y, w2.z, w2.w,
                        w3.x, w3.y, w3.z, w3.w,
                        w4.x, w4.y, w4.z, w4.w};
        #pragma unroll
        for (int bb = 0; bb < 8; bb++) {
            float4 x = *(const float4*)(X + (size_t)(b0 + bb) * FAN + i0);
            float xv[4] = {x.x, x.y, x.z, x.w};
            #pragma unroll
            for (int e = 0; e < 4; e++)
                #pragma unroll
                for (int j = 0; j < 5; j++)
                    acc[bb][j] += xv[e] * wv[e * 5 + j];
        }
    }

    #pragma unroll
    for (int off = 32; off > 0; off >>= 1)
        #pragma unroll
        for (int bb = 0; bb < 8; bb++)
            #pragma unroll
            for (int j = 0; j < 5; j++)
                acc[bb][j] += __shfl_down(acc[bb][j], off);

    __shared__ float sred[4][40];
    const int wave = t >> 6, lane = t & 63;
    if (lane == 0) {
        #pragma unroll
        for (int bb = 0; bb < 8; bb++)
            #pragma unroll
            for (int j = 0; j < 5; j++)
                sred[wave][bb * 5 + j] = acc[bb][j];
    }
    __syncthreads();
    if (t < 40) {
        float s = sred[0][t] + sred[1][t] + sred[2][t] + sred[3][t];
        atomicAdd(&ws[rep * 256 + b0 * 5 + t], s);
    }
}

// ---------------- kernel 2: build normalized filters, pre-split to bf16 hi/lo ----------------
// which==0 -> Fx [b][n][W] ; which==1 -> Fy [b][n][H]. Also zeroes `out`.
__global__ __launch_bounds__(256) void k_filters(const float* __restrict__ bl,
                                                 float* __restrict__ ws,
                                                 float* __restrict__ out) {
    const int n = blockIdx.x;
    const int b = blockIdx.y;
    const int which = blockIdx.z;
    const int t = threadIdx.x;

    // zero a 96-float slice of out (replaces the 1.5MB memset dispatch)
    {
        const int bid = blockIdx.x + NOUT * (blockIdx.y + B_ * blockIdx.z);  // 0..4095
        if (t < 24) {
            float4 z = make_float4(0.f, 0.f, 0.f, 0.f);
            ((float4*)out)[(size_t)bid * 24 + t] = z;
        }
    }

    float p0 = bl[0], p1 = bl[1], p2 = bl[2], p3 = bl[3];
    #pragma unroll
    for (int rep = 0; rep < NREP; rep++) {
        const float* pr = ws + rep * 256 + b * 5;
        p0 += pr[0]; p1 += pr[1]; p2 += pr[2]; p3 += pr[3];
    }

    const float g = (which == 0) ? 32.f * (p0 + 1.f) : 32.f * (p1 + 1.f);
    const float sigma2 = expf(p2);
    const float inv2s = 0.5f / sigma2;
    const float delta = expf(p3) * (511.0f / 63.0f);
    const float mean = g + delta * ((float)n - 32.5f);

    float d0 = (float)t - mean;
    float f0 = expf(-d0 * d0 * inv2s);
    float d1 = (float)(t + 256) - mean;
    float f1 = expf(-d1 * d1 * inv2s);

    float s = f0 + f1;
    #pragma unroll
    for (int off = 32; off > 0; off >>= 1) s += __shfl_down(s, off);
    __shared__ float sred[4];
    __shared__ float stot;
    const int wave = t >> 6, lane = t & 63;
    if (lane == 0) sred[wave] = s;
    __syncthreads();
    if (t == 0) stot = sred[0] + sred[1] + sred[2] + sred[3] + 1e-4f;
    __syncthreads();
    const float scale = 1.0f / stot;

    unsigned short* wsu = (unsigned short*)(ws + PFLOATS);
    unsigned short* dstH = wsu + (which ? FYH_U : FXH_U) + ((size_t)b * NOUT + n) * 512;
    unsigned short* dstL = wsu + (which ? FYL_U : FXL_U) + ((size_t)b * NOUT + n) * 512;

    float v0 = f0 * scale;
    unsigned short h0 = f2bf(v0);
    dstH[t] = h0;
    dstL[t] = f2bf(v0 - bf2f(h0));
    float v1 = f1 * scale;
    unsigned short h1 = f2bf(v1);
    dstH[t + 256] = h1;
    dstL[t + 256] = f2bf(v1 - bf2f(h1));
}

// ---------------- kernel 3: MFMA glimpse ----------------
// out[b,c] += gamma * Fy_chunk @ (X_chunk @ Fx^T), split-bf16 (hi+lo) MFMA.
// grid (8 hc, 96 bc), 256 threads = 4 waves.
// GEMM1: G[64h x 64m] = X[64h x 512w] @ Fx^T, staged in KC=64 w-chunks.
// GEMM2: P[64n x 64m] = Fy_chunk[64n x 64h] @ G.
// Filters arrive pre-split (hi/lo bf16) from k_filters: staging is a pure copy.
#define KC 64
#define PITCH 72            // ushorts per LDS row (16B-aligned rows, low-conflict)
#define TSZ (64 * PITCH)    // 4608 ushorts per array

__global__ __launch_bounds__(256) void k_glimpse(const float* __restrict__ X,
                                                 const float* __restrict__ bl,
                                                 const float* __restrict__ ws,
                                                 float* __restrict__ out) {
    const int hc = blockIdx.x;   // 0..7
    const int bc = blockIdx.y;   // 0..95
    const int b = bc / 3;
    const int t = threadIdx.x;
    const int lane = t & 63;
    const int wv = t >> 6;       // 0..3
    const int l15 = lane & 15;
    const int quad = lane >> 4;  // 0..3
    const int hbase = hc * 64;

    __shared__ __align__(16) unsigned short lds[4 * TSZ];   // 36864 B
    unsigned short* Xh = lds;             // X hi   -> later Gt hi
    unsigned short* Xl = lds + TSZ;       // X lo   -> later Gt lo
    unsigned short* Fh = lds + 2 * TSZ;   // Fx hi  -> later Fy hi
    unsigned short* Fl = lds + 3 * TSZ;   // Fx lo  -> later Fy lo

    const float* Xp = X + (size_t)bc * (H_ * W_) + (size_t)hbase * W_;
    const unsigned short* wsu = (const unsigned short*)(ws + PFLOATS);
    const unsigned short* FxHp = wsu + FXH_U + (size_t)b * NOUT * 512;
    const unsigned short* FxLp = wsu + FXL_U + (size_t)b * NOUT * 512;
    const unsigned short* FyHp = wsu + FYH_U + (size_t)b * NOUT * 512;
    const unsigned short* FyLp = wsu + FYL_U + (size_t)b * NOUT * 512;

    f32x4 acc[4] = {};   // G: wave rows [16wv,+16), 4 m-tiles

    for (int wt = 0; wt < 8; wt++) {
        const int wbase = wt * KC;
        // stage X chunk: fp32 -> packed bf16 hi/lo via v_cvt_pk_bf16_f32
        #pragma unroll
        for (int k4 = 0; k4 < 4; k4++) {
            int idx = t + 256 * k4;
            int row = idx >> 4;            // 0..63
            int c4 = (idx & 15) * 4;       // 0,4,..60
            float4 xv = *(const float4*)(Xp + (size_t)row * W_ + wbase + c4);
            unsigned int h01 = cvt_pk_bf16(xv.x, xv.y);
            unsigned int h23 = cvt_pk_bf16(xv.z, xv.w);
            float r0 = __uint_as_float(h01 << 16);
            float r1 = __uint_as_float(h01 & 0xffff0000u);
            float r2 = __uint_as_float(h23 << 16);
            float r3 = __uint_as_float(h23 & 0xffff0000u);
            unsigned int l01 = cvt_pk_bf16(xv.x - r0, xv.y - r1);
            unsigned int l23 = cvt_pk_bf16(xv.z - r2, xv.w - r3);
            int o = row * PITCH + c4;
            *(uint2*)&Xh[o] = make_uint2(h01, h23);
            *(uint2*)&Xl[o] = make_uint2(l01, l23);
        }
        // stage Fx chunk: pure 16B copies of precomputed hi/lo
        #pragma unroll
        for (int i = 0; i < 2; i++) {
            int idx = t + 256 * i;         // 0..511
            int row = idx >> 3;            // 0..63
            int c8 = (idx & 7) * 8;        // 0,8,..56
            uint4 hv = *(const uint4*)(FxHp + (size_t)row * 512 + wbase + c8);
            uint4 lv = *(const uint4*)(FxLp + (size_t)row * 512 + wbase + c8);
            *(uint4*)&Fh[row * PITCH + c8] = hv;
            *(uint4*)&Fl[row * PITCH + c8] = lv;
        }
        __syncthreads();
        #pragma unroll
        for (int ks = 0; ks < 2; ks++) {
            const int ko = ks * 32 + quad * 8;
            bf16x8 ah = *(const bf16x8*)&Xh[(16 * wv + l15) * PITCH + ko];
            bf16x8 al = *(const bf16x8*)&Xl[(16 * wv + l15) * PITCH + ko];
            #pragma unroll
            for (int mt = 0; mt < 4; mt++) {
                bf16x8 bh = *(const bf16x8*)&Fh[(16 * mt + l15) * PITCH + ko];
                bf16x8 bl2 = *(const bf16x8*)&Fl[(16 * mt + l15) * PITCH + ko];
                acc[mt] = __builtin_amdgcn_mfma_f32_16x16x32_bf16(ah, bh, acc[mt], 0, 0, 0);
                acc[mt] = __builtin_amdgcn_mfma_f32_16x16x32_bf16(al, bh, acc[mt], 0, 0, 0);
                acc[mt] = __builtin_amdgcn_mfma_f32_16x16x32_bf16(ah, bl2, acc[mt], 0, 0, 0);
            }
        }
        __syncthreads();
    }

    // write G transposed as hi/lo into Xh/Xl region: Gt[m][h]
    #pragma unroll
    for (int mt = 0; mt < 4; mt++) {
        float g0 = acc[mt][0], g1 = acc[mt][1], g2 = acc[mt][2], g3 = acc[mt][3];
        unsigned int h01 = cvt_pk_bf16(g0, g1);
        unsigned int h23 = cvt_pk_bf16(g2, g3);
        float r0 = __uint_as_float(h01 << 16);
        float r1 = __uint_as_float(h01 & 0xffff0000u);
        float r2 = __uint_as_float(h23 << 16);
        float r3 = __uint_as_float(h23 & 0xffff0000u);
        unsigned int l01 = cvt_pk_bf16(g0 - r0, g1 - r1);
        unsigned int l23 = cvt_pk_bf16(g2 - r2, g3 - r3);
        int m = 16 * mt + l15;
        int h = 16 * wv + quad * 4;      // rows quad*4+r, r contiguous
        int o = m * PITCH + h;
        *(uint2*)&Xh[o] = make_uint2(h01, h23);
        *(uint2*)&Xl[o] = make_uint2(l01, l23);
    }

    // stage Fy chunk hi/lo into Fh/Fl: pure copies of precomputed split
    #pragma unroll
    for (int i = 0; i < 2; i++) {
        int idx = t + 256 * i;
        int row = idx >> 3;               // n: 0..63
        int c8 = (idx & 7) * 8;           // local h: 0,8,..56
        uint4 hv = *(const uint4*)(FyHp + (size_t)row * 512 + hbase + c8);
        uint4 lv = *(const uint4*)(FyLp + (size_t)row * 512 + hbase + c8);
        *(uint4*)&Fh[row * PITCH + c8] = hv;
        *(uint4*)&Fl[row * PITCH + c8] = lv;
    }
    __syncthreads();

    // GEMM2: P[n][m] = sum_h Fy[n][h] * G[h][m]
    f32x4 p[4] = {};
    #pragma unroll
    for (int ks = 0; ks < 2; ks++) {
        const int ko = ks * 32 + quad * 8;
        bf16x8 yh = *(const bf16x8*)&Fh[(16 * wv + l15) * PITCH + ko];
        bf16x8 yl = *(const bf16x8*)&Fl[(16 * wv + l15) * PITCH + ko];
        #pragma unroll
        for (int mt = 0; mt < 4; mt++) {
            bf16x8 gh = *(const bf16x8*)&Xh[(16 * mt + l15) * PITCH + ko];
            bf16x8 gl = *(const bf16x8*)&Xl[(16 * mt + l15) * PITCH + ko];
            p[mt] = __builtin_amdgcn_mfma_f32_16x16x32_bf16(yh, gh, p[mt], 0, 0, 0);
            p[mt] = __builtin_amdgcn_mfma_f32_16x16x32_bf16(yl, gh, p[mt], 0, 0, 0);
            p[mt] = __builtin_amdgcn_mfma_f32_16x16x32_bf16(yh, gl, p[mt], 0, 0, 0);
        }
    }

    float p4 = bl[4];
    #pragma unroll
    for (int rep = 0; rep < NREP; rep++) p4 += ws[rep * 256 + b * 5 + 4];
    const float gamma = expf(p4);

    float* outp = out + (size_t)bc * (NOUT * NOUT);
    #pragma unroll
    for (int mt = 0; mt < 4; mt++)
        #pragma unroll
        for (int r = 0; r < 4; r++) {
            int n = 16 * wv + quad * 4 + r;
            int m = 16 * mt + l15;
            atomicAdd(&outp[n * NOUT + m], gamma * p[mt][r]);
        }
}

extern "C" void kernel_launch(void* const* d_in, const int* in_sizes, int n_in,
                              void* d_out, int out_size, void* d_ws, size_t ws_size,
                              hipStream_t stream) {
    const float* X  = (const float*)d_in[0];
    const float* Wl = (const float*)d_in[1];
    const float* bl = (const float*)d_in[2];
    float* out = (float*)d_out;
    float* ws  = (float*)d_ws;

    hipMemsetAsync(ws, 0, PFLOATS * sizeof(float), stream);

    k_locnet<<<dim3(CHUNKS, BGROUPS), 256, 0, stream>>>(X, Wl, ws);
    k_filters<<<dim3(NOUT, B_, 2), 256, 0, stream>>>(bl, ws, out);
    k_glimpse<<<dim3(8, B_ * C_), 256, 0, stream>>>(X, bl, ws, out);
}